// Round 5
// baseline (295.592 us; speedup 1.0000x reference)
//
#include <hip/hip_runtime.h>
#include <hip/hip_bf16.h>
#include <cstddef>

#define T_DIM 16384
#define B_DIM 4
#define RC 32
#define DC 32
#define COND 80
#define SC 256
#define CLASSES 256
#define NLAYERS 40

#define TILE_W 128
#define HALO 40            // exact receptive field of 40 K=2 causal layers
#define TILE_OUT 88
#define NT 187             // ceil(16384/88)

// act row layout (bf16 units): [resb 32 | y/z 32 | h 80 | zero 16 | pad 8]
// AS=168 -> 84-dword stride. CH_Z region (y/z) is now register-resident; the
// LDS slots remain (unwritten) so all other offsets match the proven R0 layout.
#define AS 168
#define CH_RH 0
#define CH_Z 32
#define CH_H 64
#define CH_ZERO 144

#define WPL2 11264          // packed bf16 weights per layer
#define G2_OFF 2048
#define G4_OFF 10240

typedef __bf16 bf16x8 __attribute__((ext_vector_type(8)));
typedef float f32x4 __attribute__((ext_vector_type(4)));

__device__ __forceinline__ unsigned f2bfbits(float f) {
    unsigned u = __float_as_uint(f);
    return (u + 0x7FFFu + ((u >> 16) & 1u)) >> 16;
}
// packed RNE f32x2 -> bf16x2
__device__ __forceinline__ unsigned pk2(float a, float b) {
    __hip_bfloat162 v = __float22bfloat162_rn(make_float2(a, b));
    union { __hip_bfloat162 h; unsigned u; } cv;
    cv.h = v;
    return cv.u;
}
__device__ __forceinline__ f32x4 mfma16(bf16x8 a, bf16x8 b, f32x4 c) {
    return __builtin_amdgcn_mfma_f32_16x16x32_bf16(a, b, c, 0, 0, 0);
}

// pi: k-order permutation for register-built B-frags (y and z paths).
// Lane quad q holds dwords {own(j=0,1) | swz16(j=2,3) | own(j=4,5) | swz16(j=6,7)}
// of the C-layout channels; k = q*8+j maps to channel:
__device__ __forceinline__ int pi_ch(int q, int j) {
    int jj = j & 3;
    int qq = (jj >= 2) ? (q ^ 1) : q;
    return (j >> 2) * 16 + 4 * qq + jj;
}

// ---- weight pack: A-operand fragment order (m=lane&15, k=(lane>>4)*8+j), bf16
// GEMM2 rows pre-scaled: f rows by 2*log2(e), g rows by log2(e) -> glue uses
// exp2 directly. GEMM2 kt==0 (y) and GEMM4 k-order are pi-permuted to match
// the register-built B fragments.
__global__ __launch_bounds__(256) void pack_kernel(
    const float* __restrict__ dw, const float* __restrict__ fw,
    const float* __restrict__ gw, const float* __restrict__ cfw,
    const float* __restrict__ cgw, const float* __restrict__ ow,
    const float* __restrict__ e1, const float* __restrict__ e2,
    unsigned short* __restrict__ wpk, unsigned short* __restrict__ e1pk,
    unsigned short* __restrict__ e2pk)
{
    int idx = blockIdx.x * 256 + threadIdx.x;      // 524,288 total exactly
    if (idx < NLAYERS * WPL2) {
        int l = idx / WPL2, o = idx % WPL2;
        float v;
        if (o < G2_OFF) {                          // conv: tile = mt*2+ks
            int t = o >> 9, li = o & 511;
            int mt = t >> 1, ks = t & 1;
            int lane = li >> 3, j = li & 7;
            int m = lane & 15, q = lane >> 4;
            int d = mt * 16 + m, r = q * 8 + j;
            v = dw[((l * 32 + d) * 32 + r) * 2 + ks];
        } else if (o < G4_OFF) {                   // gated+cond: tile = mt*4+kt
            int o2 = o - G2_OFF;
            int t = o2 >> 9, li = o2 & 511;
            int mt = t >> 2, kt = t & 3;
            int lane = li >> 3, j = li & 7;
            int m = lane & 15, q = lane >> 4;
            int row = mt * 16 + m;                 // 0..31 = f, 32..63 = g
            int d = row & 31;
            int kk;
            if (kt == 0) kk = pi_ch(q, j);         // y from registers: pi order
            else         kk = kt * 32 + q * 8 + j; // h path: natural order
            if (kk < 32)       v = (row < 32 ? fw : gw)[(l * 32 + d) * 32 + kk];
            else if (kk < 112) v = (row < 32 ? cfw : cgw)[(l * 32 + d) * 80 + (kk - 32)];
            else               v = 0.f;
            v *= (row < 32) ? 2.8853900817779268f : 1.4426950408889634f;
        } else {                                   // out 1x1: tile = mt (z in regs: pi)
            int o3 = o - G4_OFF;
            int mt = o3 >> 9, li = o3 & 511;
            int lane = li >> 3, j = li & 7;
            int m = lane & 15, q = lane >> 4;
            int r = mt * 16 + m, d = pi_ch(q, j);
            v = ow[(l * 32 + r) * 32 + d];
        }
        wpk[idx] = (unsigned short)f2bfbits(v);
    } else if (idx < NLAYERS * WPL2 + 16 * 512) {  // e1pk: 16 m-tiles, K=32
        int o = idx - NLAYERS * WPL2;
        int mt = o >> 9, li = o & 511;
        int lane = li >> 3, j = li & 7;
        int m = lane & 15, q = lane >> 4;
        int s = mt * 16 + m, c = q * 8 + j;
        e1pk[o] = (unsigned short)f2bfbits(e1[s * RC + c]);
    } else {                                       // e2pk: (mt*8+kf) tiles
        int o = idx - NLAYERS * WPL2 - 16 * 512;   // < 65536 exactly
        int t = o >> 9, li = o & 511;
        int mt = t >> 3, kf = t & 7;
        int lane = li >> 3, j = li & 7;
        int m = lane & 15, q = lane >> 4;
        int cls = mt * 16 + m, k = kf * 32 + q * 8 + j;
        e2pk[o] = (unsigned short)f2bfbits(e2[cls * SC + k]);
    }
}

// ---- all 40 layers, MFMA. EXACT R0 skeleton (2 barriers/layer, act[] layout,
// per-use weight loads) with y and z kept in registers (pk2 + ds_swizzle
// lane^16, pi-packed weights) instead of LDS round-trips, and exp2 glue.
__global__ __launch_bounds__(256, 3) void fused_mfma_kernel(
    const float* __restrict__ x, const float* __restrict__ h,
    const float* __restrict__ sw, const unsigned short* __restrict__ wpk,
    float* __restrict__ skip_out)
{
    __shared__ unsigned short act[TILE_W * AS];    // 43,008 B -> 3 blocks/CU

    const int tid  = threadIdx.x;
    const int lane = tid & 63;
    const int wave = tid >> 6;
    const int quad = lane >> 4;
    const int l16  = lane & 15;
    const int b    = blockIdx.x / NT;
    const int tile = blockIdx.x % NT;
    const int tbase = tile * TILE_OUT - HALO;
    const bool tile0 = (tile == 0);

    // stage h as bf16 (clamped both edges) + zero the K-pad region
    {
        const int col = tid & 127;
        const int half = tid >> 7;
        const int gtc = min(max(tbase + col, 0), T_DIM - 1);
        const float* hp = h + (size_t)b * COND * T_DIM + gtc;
        for (int j = half; j < COND; j += 2)
            act[col * AS + CH_H + j] = (unsigned short)f2bfbits(hp[(size_t)j * T_DIM]);
        *(uint4*)(act + col * AS + CH_ZERO + half * 8) = make_uint4(0u, 0u, 0u, 0u);
    }

    // residual registers: lane owns (ch = mt*16+quad*4+r, col = wave*32+nt*16+l16)
    const f32x4 zero4 = {0.f, 0.f, 0.f, 0.f};
    float xv[2], mskv[2];
    float swr[2][4];
    f32x4 res[2][2];

#pragma unroll
    for (int nt = 0; nt < 2; nt++) {
        int gt = tbase + wave * 32 + nt * 16 + l16;
        int gx = min(max(gt, 0), T_DIM - 1);
        float v = x[(size_t)b * T_DIM + gx];
        mskv[nt] = (gt >= 0) ? 1.f : 0.f;
        xv[nt] = v * mskv[nt];
    }
#pragma unroll
    for (int mt = 0; mt < 2; mt++)
#pragma unroll
        for (int r = 0; r < 4; r++)
            swr[mt][r] = sw[mt * 16 + quad * 4 + r];
#pragma unroll
    for (int mt = 0; mt < 2; mt++)
#pragma unroll
        for (int nt = 0; nt < 2; nt++) {
#pragma unroll
            for (int r = 0; r < 4; r++) res[mt][nt][r] = swr[mt][r] * xv[nt];
            const int c = wave * 32 + nt * 16 + l16;
            const int ch0 = mt * 16 + quad * 4;
            unsigned h0 = pk2(res[mt][nt][0], res[mt][nt][1]);
            unsigned h1 = pk2(res[mt][nt][2], res[mt][nt][3]);
            *(uint2*)(act + c * AS + CH_RH + ch0) = make_uint2(h0, h1);
        }
    __syncthreads();

    const unsigned short* wl = wpk;
    for (int l = 0; l < NLAYERS; l++, wl += WPL2) {
        // conv B-frags (prv needs col-1 -> cross-wave; read BEFORE barrier)
        bf16x8 bc[2][2];   // [ks: prv/cur][nt]
#pragma unroll
        for (int nt = 0; nt < 2; nt++) {
            const int c = wave * 32 + nt * 16 + l16;
            const int cp = max(c - 1, 0);
            bc[0][nt] = *(const bf16x8*)(act + cp * AS + CH_RH + quad * 8);
            bc[1][nt] = *(const bf16x8*)(act + c  * AS + CH_RH + quad * 8);
        }
        __syncthreads();   // A: conv reads done before this layer's resb writes

        // GEMM1: y[32] = Wdil . [prv;cur]
        f32x4 acc1[2][2];
#pragma unroll
        for (int mt = 0; mt < 2; mt++)
#pragma unroll
            for (int nt = 0; nt < 2; nt++) acc1[mt][nt] = zero4;
#pragma unroll
        for (int ks = 0; ks < 2; ks++)
#pragma unroll
            for (int mt = 0; mt < 2; mt++) {
                bf16x8 a = *(const bf16x8*)(wl + (mt * 2 + ks) * 512 + lane * 8);
#pragma unroll
                for (int nt = 0; nt < 2; nt++)
                    acc1[mt][nt] = mfma16(a, bc[ks][nt], acc1[mt][nt]);
            }

        // y C-layout -> B-frag entirely in registers (pi order); swizzles
        // issued here, consumed after the independent h-part MFMAs below.
        bf16x8 by[2];
#pragma unroll
        for (int nt = 0; nt < 2; nt++) {
            union { unsigned u[4]; bf16x8 v; } cv;
            unsigned a0 = pk2(acc1[0][nt][0], acc1[0][nt][1]);
            unsigned b0 = pk2(acc1[0][nt][2], acc1[0][nt][3]);
            unsigned c0 = pk2(acc1[1][nt][0], acc1[1][nt][1]);
            unsigned d0 = pk2(acc1[1][nt][2], acc1[1][nt][3]);
            cv.u[0] = a0;
            cv.u[1] = (unsigned)__builtin_amdgcn_ds_swizzle((int)b0, 0x401F); // lane^16
            cv.u[2] = c0;
            cv.u[3] = (unsigned)__builtin_amdgcn_ds_swizzle((int)d0, 0x401F);
            by[nt] = cv.v;
        }

        // GEMM2: [f;g] = W . [y | h | 0]  (M=64, K=128)
        // h-part (kt=1..3, from LDS as in R0) first; y-part (regs) last.
        f32x4 acc2[4][2];
#pragma unroll
        for (int kt = 1; kt < 4; kt++) {
            bf16x8 bb[2];
#pragma unroll
            for (int nt = 0; nt < 2; nt++) {
                const int c = wave * 32 + nt * 16 + l16;
                bb[nt] = *(const bf16x8*)(act + c * AS + CH_Z + kt * 32 + quad * 8);
            }
#pragma unroll
            for (int mt = 0; mt < 4; mt++) {
                bf16x8 a = *(const bf16x8*)(wl + G2_OFF + (mt * 4 + kt) * 512 + lane * 8);
#pragma unroll
                for (int nt = 0; nt < 2; nt++)
                    acc2[mt][nt] = (kt == 1) ? mfma16(a, bb[nt], zero4)
                                             : mfma16(a, bb[nt], acc2[mt][nt]);
            }
        }
#pragma unroll
        for (int mt = 0; mt < 4; mt++) {
            bf16x8 a = *(const bf16x8*)(wl + G2_OFF + (mt * 4) * 512 + lane * 8);
#pragma unroll
            for (int nt = 0; nt < 2; nt++)
                acc2[mt][nt] = mfma16(a, by[nt], acc2[mt][nt]);
        }

        // glue: z = tanh(f)*sigmoid(g) with pre-scaled logits (exp2 form):
        // F=2log2e*f<=64, G=log2e*g<=22; z=(2^F-1)*2^G / ((2^F+1)(2^G+1));
        // denom <= 7.7e25 finite, single rcp, no NaN path.
        bf16x8 bz[2];
#pragma unroll
        for (int nt = 0; nt < 2; nt++) {
            float z[2][4];
#pragma unroll
            for (int mt = 0; mt < 2; mt++)
#pragma unroll
                for (int r = 0; r < 4; r++) {
                    float fa = fminf(acc2[mt][nt][r], 64.f);
                    float ga = fminf(acc2[mt + 2][nt][r], 22.f);
                    float ef = exp2f(fa);
                    float eg = exp2f(ga);
                    float rr = __builtin_amdgcn_rcpf((ef + 1.f) * (eg + 1.f));
                    z[mt][r] = (ef - 1.f) * eg * rr;
                }
            union { unsigned u[4]; bf16x8 v; } cv;
            unsigned a0 = pk2(z[0][0], z[0][1]);
            unsigned b0 = pk2(z[0][2], z[0][3]);
            unsigned c0 = pk2(z[1][0], z[1][1]);
            unsigned d0 = pk2(z[1][2], z[1][3]);
            cv.u[0] = a0;
            cv.u[1] = (unsigned)__builtin_amdgcn_ds_swizzle((int)b0, 0x401F);
            cv.u[2] = c0;
            cv.u[3] = (unsigned)__builtin_amdgcn_ds_swizzle((int)d0, 0x401F);
            bz[nt] = cv.v;
        }

        // GEMM4: out[32] = Wout . z  (A packed in pi order)
        f32x4 acc4[2][2];
#pragma unroll
        for (int mt = 0; mt < 2; mt++) {
            bf16x8 a = *(const bf16x8*)(wl + G4_OFF + mt * 512 + lane * 8);
#pragma unroll
            for (int nt = 0; nt < 2; nt++)
                acc4[mt][nt] = mfma16(a, bz[nt], zero4);
        }

        // residual update (fp32 regs) + resb write; mask only on tile 0
#pragma unroll
        for (int mt = 0; mt < 2; mt++)
#pragma unroll
            for (int nt = 0; nt < 2; nt++) {
                const int c = wave * 32 + nt * 16 + l16;
                const int ch0 = mt * 16 + quad * 4;
                f32x4 nr = res[mt][nt] + acc4[mt][nt];
                if (tile0 && wave < 2) nr = nr * mskv[nt];   // block/wave-uniform branch
                res[mt][nt] = nr;
                unsigned h0 = pk2(nr[0], nr[1]);
                unsigned h1 = pk2(nr[2], nr[3]);
                *(uint2*)(act + c * AS + CH_RH + ch0) = make_uint2(h0, h1);
            }
        __syncthreads();   // B: resb writes visible before next layer's reads
    }

    // epilogue: skip = res_final - res_0 (cols >= HALO, in range)
#pragma unroll
    for (int mt = 0; mt < 2; mt++)
#pragma unroll
        for (int nt = 0; nt < 2; nt++) {
            const int c = wave * 32 + nt * 16 + l16;
            const int gt = tbase + c;
            if (c >= HALO && gt < T_DIM) {
#pragma unroll
                for (int r = 0; r < 4; r++) {
                    const int ch = mt * 16 + quad * 4 + r;
                    skip_out[((size_t)b * RC + ch) * T_DIM + gt] =
                        res[mt][nt][r] - swr[mt][r] * xv[nt];
                }
            }
        }
}

// ---- end: relu->e1->relu->e2 with MFMA (bf16). Block = 64 cols, M=256.
__global__ __launch_bounds__(256) void end_kernel(
    const float* __restrict__ skip,          // [B,32,T]
    const unsigned short* __restrict__ e1pk, // A-frags [16 mt][512]
    const unsigned short* __restrict__ e2pk, // A-frags [16 mt * 8 kf][512]
    float* __restrict__ outp)                // [B][256][T]
{
    __shared__ unsigned short sk_s[64 * 40];    // [col][ch], pad 32->40
    __shared__ unsigned short e_s[64 * 264];    // [col][s], pad 256->264

    const int tid  = threadIdx.x;
    const int lane = tid & 63;
    const int wave = tid >> 6;
    const int quad = lane >> 4;
    const int l16  = lane & 15;
    const int b  = blockIdx.x >> 8;
    const int t0 = (blockIdx.x & 255) * 64;

    // stage relu(skip) -> bf16 [col][ch]
    {
        const int col = tid & 63;
        const int cg = tid >> 6;           // 4 channel groups of 8
        const float* sp = skip + ((size_t)b * RC + cg * 8) * T_DIM + t0 + col;
        float v[8];
#pragma unroll
        for (int k = 0; k < 8; k++)
            v[k] = fmaxf(sp[(size_t)k * T_DIM], 0.f);
        unsigned u0 = pk2(v[0], v[1]), u1 = pk2(v[2], v[3]);
        unsigned u2 = pk2(v[4], v[5]), u3 = pk2(v[6], v[7]);
        *(uint2*)(sk_s + col * 40 + cg * 8)     = make_uint2(u0, u1);
        *(uint2*)(sk_s + col * 40 + cg * 8 + 4) = make_uint2(u2, u3);
    }
    __syncthreads();

    // phase 1: e[256 s][64 col] = relu(e1 . sk) ; wave handles 4 m-tiles
    {
        bf16x8 bb[4];
#pragma unroll
        for (int ntl = 0; ntl < 4; ntl++)
            bb[ntl] = *(const bf16x8*)(sk_s + (ntl * 16 + l16) * 40 + quad * 8);
#pragma unroll
        for (int mtl = 0; mtl < 4; mtl++) {
            const int mt = wave * 4 + mtl;
            bf16x8 a = *(const bf16x8*)(e1pk + mt * 512 + lane * 8);
            f32x4 acc[4];
#pragma unroll
            for (int ntl = 0; ntl < 4; ntl++) {
                acc[ntl] = mfma16(a, bb[ntl], (f32x4){0.f, 0.f, 0.f, 0.f});
            }
#pragma unroll
            for (int ntl = 0; ntl < 4; ntl++) {
                const int col = ntl * 16 + l16;
                unsigned p0 = pk2(fmaxf(acc[ntl][0], 0.f), fmaxf(acc[ntl][1], 0.f));
                unsigned p1 = pk2(fmaxf(acc[ntl][2], 0.f), fmaxf(acc[ntl][3], 0.f));
                *(uint2*)(e_s + col * 264 + mt * 16 + quad * 4) = make_uint2(p0, p1);
            }
        }
    }
    __syncthreads();

    // phase 2: logits[256 cls][64 col] = e2 . e ; wave: 4 m-tiles x 4 n x 8 k
    {
        f32x4 acc[4][4];
#pragma unroll
        for (int mtl = 0; mtl < 4; mtl++)
#pragma unroll
            for (int ntl = 0; ntl < 4; ntl++) acc[mtl][ntl] = (f32x4){0.f, 0.f, 0.f, 0.f};

        for (int kf = 0; kf < 8; kf++) {
            bf16x8 bb[4];
#pragma unroll
            for (int ntl = 0; ntl < 4; ntl++)
                bb[ntl] = *(const bf16x8*)(e_s + (ntl * 16 + l16) * 264 + kf * 32 + quad * 8);
#pragma unroll
            for (int mtl = 0; mtl < 4; mtl++) {
                const int mt = wave * 4 + mtl;
                bf16x8 a = *(const bf16x8*)(e2pk + (mt * 8 + kf) * 512 + lane * 8);
#pragma unroll
                for (int ntl = 0; ntl < 4; ntl++)
                    acc[mtl][ntl] = mfma16(a, bb[ntl], acc[mtl][ntl]);
            }
        }

#pragma unroll
        for (int mtl = 0; mtl < 4; mtl++)
#pragma unroll
            for (int ntl = 0; ntl < 4; ntl++) {
                const int cls0 = (wave * 4 + mtl) * 16 + quad * 4;
                const int col = ntl * 16 + l16;
#pragma unroll
                for (int r = 0; r < 4; r++)
                    outp[((size_t)b * CLASSES + cls0 + r) * T_DIM + t0 + col] =
                        acc[mtl][ntl][r];
            }
    }
}

extern "C" void kernel_launch(void* const* d_in, const int* in_sizes, int n_in,
                              void* d_out, int out_size, void* d_ws, size_t ws_size,
                              hipStream_t stream) {
    const float* x   = (const float*)d_in[0];
    const float* h   = (const float*)d_in[1];
    const float* sw  = (const float*)d_in[2];
    const float* dw  = (const float*)d_in[3];
    const float* fw  = (const float*)d_in[4];
    const float* gw  = (const float*)d_in[5];
    const float* cfw = (const float*)d_in[6];
    const float* cgw = (const float*)d_in[7];
    const float* ow  = (const float*)d_in[8];
    const float* e1  = (const float*)d_in[9];
    const float* e2  = (const float*)d_in[10];
    float* out = (float*)d_out;

    const size_t SKIP_N = (size_t)B_DIM * RC * T_DIM;   // 2,097,152 floats
    float* skip = (float*)d_ws;
    unsigned short* wpk  = (unsigned short*)(skip + SKIP_N);
    unsigned short* e1pk = wpk + (size_t)NLAYERS * WPL2;
    unsigned short* e2pk = e1pk + 16 * 512;

    // 450,560 + 8,192 + 65,536 = 524,288 -> 2048 blocks exactly
    pack_kernel<<<2048, 256, 0, stream>>>(dw, fw, gw, cfw, cgw, ow, e1, e2,
                                          wpk, e1pk, e2pk);

    fused_mfma_kernel<<<B_DIM * NT, 256, 0, stream>>>(x, h, sw, wpk, skip);

    end_kernel<<<B_DIM * 256, 256, 0, stream>>>(skip, e1pk, e2pk, out);
}

// Round 6
// 261.695 us; speedup vs baseline: 1.1295x; 1.1295x over previous
//
#include <hip/hip_runtime.h>
#include <hip/hip_bf16.h>
#include <cstddef>

#define T_DIM 16384
#define B_DIM 4
#define RC 32
#define DC 32
#define COND 80
#define SC 256
#define CLASSES 256
#define NLAYERS 40

#define TILE_W 128
#define HALO 40            // exact receptive field of 40 K=2 causal layers
#define TILE_OUT 88
#define NT 187             // ceil(16384/88)

// act row layout (bf16 units): [resb 32 | y/z 32 | h 80 | zero 16 | pad 8]
// AS=168 -> 84-dword stride. CH_Z y/z slots are register-resident now; offsets
// kept identical to the proven R0 layout.
#define AS 168
#define CH_RH 0
#define CH_Z 32
#define CH_H 64
#define CH_ZERO 144

#define WPL2 11264          // packed bf16 weights per layer
#define G2_OFF 2048
#define G4_OFF 10240

typedef __bf16 bf16x8 __attribute__((ext_vector_type(8)));
typedef float f32x4 __attribute__((ext_vector_type(4)));

__device__ __forceinline__ unsigned f2bfbits(float f) {
    unsigned u = __float_as_uint(f);
    return (u + 0x7FFFu + ((u >> 16) & 1u)) >> 16;
}
// packed RNE f32x2 -> bf16x2
__device__ __forceinline__ unsigned pk2(float a, float b) {
    __hip_bfloat162 v = __float22bfloat162_rn(make_float2(a, b));
    union { __hip_bfloat162 h; unsigned u; } cv;
    cv.h = v;
    return cv.u;
}
__device__ __forceinline__ f32x4 mfma16(bf16x8 a, bf16x8 b, f32x4 c) {
    return __builtin_amdgcn_mfma_f32_16x16x32_bf16(a, b, c, 0, 0, 0);
}

// pi: k-order permutation for register-built B-frags (y and z paths).
// Lane quad q holds dwords {own(j=0,1) | swz16(j=2,3) | own(j=4,5) | swz16(j=6,7)}
// of the C-layout channels; k = q*8+j maps to channel:
__device__ __forceinline__ int pi_ch(int q, int j) {
    int jj = j & 3;
    int qq = (jj >= 2) ? (q ^ 1) : q;
    return (j >> 2) * 16 + 4 * qq + jj;
}

// ---- weight pack: A-operand fragment order (m=lane&15, k=(lane>>4)*8+j), bf16
// GEMM2 rows pre-scaled: f rows by 2*log2(e), g rows by log2(e) -> glue uses
// raw v_exp_f32 (2^x) directly. GEMM2 kt==0 (y) and GEMM4 k-order are
// pi-permuted to match the register-built B fragments.
__global__ __launch_bounds__(256) void pack_kernel(
    const float* __restrict__ dw, const float* __restrict__ fw,
    const float* __restrict__ gw, const float* __restrict__ cfw,
    const float* __restrict__ cgw, const float* __restrict__ ow,
    const float* __restrict__ e1, const float* __restrict__ e2,
    unsigned short* __restrict__ wpk, unsigned short* __restrict__ e1pk,
    unsigned short* __restrict__ e2pk)
{
    int idx = blockIdx.x * 256 + threadIdx.x;      // 524,288 total exactly
    if (idx < NLAYERS * WPL2) {
        int l = idx / WPL2, o = idx % WPL2;
        float v;
        if (o < G2_OFF) {                          // conv: tile = mt*2+ks
            int t = o >> 9, li = o & 511;
            int mt = t >> 1, ks = t & 1;
            int lane = li >> 3, j = li & 7;
            int m = lane & 15, q = lane >> 4;
            int d = mt * 16 + m, r = q * 8 + j;
            v = dw[((l * 32 + d) * 32 + r) * 2 + ks];
        } else if (o < G4_OFF) {                   // gated+cond: tile = mt*4+kt
            int o2 = o - G2_OFF;
            int t = o2 >> 9, li = o2 & 511;
            int mt = t >> 2, kt = t & 3;
            int lane = li >> 3, j = li & 7;
            int m = lane & 15, q = lane >> 4;
            int row = mt * 16 + m;                 // 0..31 = f, 32..63 = g
            int d = row & 31;
            int kk;
            if (kt == 0) kk = pi_ch(q, j);         // y from registers: pi order
            else         kk = kt * 32 + q * 8 + j; // h path: natural order
            if (kk < 32)       v = (row < 32 ? fw : gw)[(l * 32 + d) * 32 + kk];
            else if (kk < 112) v = (row < 32 ? cfw : cgw)[(l * 32 + d) * 80 + (kk - 32)];
            else               v = 0.f;
            v *= (row < 32) ? 2.8853900817779268f : 1.4426950408889634f;
        } else {                                   // out 1x1: tile = mt (z in regs: pi)
            int o3 = o - G4_OFF;
            int mt = o3 >> 9, li = o3 & 511;
            int lane = li >> 3, j = li & 7;
            int m = lane & 15, q = lane >> 4;
            int r = mt * 16 + m, d = pi_ch(q, j);
            v = ow[(l * 32 + r) * 32 + d];
        }
        wpk[idx] = (unsigned short)f2bfbits(v);
    } else if (idx < NLAYERS * WPL2 + 16 * 512) {  // e1pk: 16 m-tiles, K=32
        int o = idx - NLAYERS * WPL2;
        int mt = o >> 9, li = o & 511;
        int lane = li >> 3, j = li & 7;
        int m = lane & 15, q = lane >> 4;
        int s = mt * 16 + m, c = q * 8 + j;
        e1pk[o] = (unsigned short)f2bfbits(e1[s * RC + c]);
    } else {                                       // e2pk: (mt*8+kf) tiles
        int o = idx - NLAYERS * WPL2 - 16 * 512;   // < 65536 exactly
        int t = o >> 9, li = o & 511;
        int mt = t >> 3, kf = t & 7;
        int lane = li >> 3, j = li & 7;
        int m = lane & 15, q = lane >> 4;
        int cls = mt * 16 + m, k = kf * 32 + q * 8 + j;
        e2pk[o] = (unsigned short)f2bfbits(e2[cls * SC + k]);
    }
}

// ---- all 40 layers, MFMA. R0 skeleton (2 barriers/layer, act[] layout,
// per-use weight loads) + register-resident y/z (pk2 + ds_swizzle lane^16,
// pi-packed weights) + native-exp2 glue (__builtin_amdgcn_exp2f, NOT the
// precise libm exp2f which costs ~15 VALU/call -- R5's measured regression).
__global__ __launch_bounds__(256, 3) void fused_mfma_kernel(
    const float* __restrict__ x, const float* __restrict__ h,
    const float* __restrict__ sw, const unsigned short* __restrict__ wpk,
    float* __restrict__ skip_out)
{
    __shared__ unsigned short act[TILE_W * AS];    // 43,008 B -> 3 blocks/CU

    const int tid  = threadIdx.x;
    const int lane = tid & 63;
    const int wave = tid >> 6;
    const int quad = lane >> 4;
    const int l16  = lane & 15;
    const int b    = blockIdx.x / NT;
    const int tile = blockIdx.x % NT;
    const int tbase = tile * TILE_OUT - HALO;
    const bool tile0 = (tile == 0);

    // stage h as bf16 (clamped both edges) + zero the K-pad region
    {
        const int col = tid & 127;
        const int half = tid >> 7;
        const int gtc = min(max(tbase + col, 0), T_DIM - 1);
        const float* hp = h + (size_t)b * COND * T_DIM + gtc;
        for (int j = half; j < COND; j += 2)
            act[col * AS + CH_H + j] = (unsigned short)f2bfbits(hp[(size_t)j * T_DIM]);
        *(uint4*)(act + col * AS + CH_ZERO + half * 8) = make_uint4(0u, 0u, 0u, 0u);
    }

    // residual registers: lane owns (ch = mt*16+quad*4+r, col = wave*32+nt*16+l16)
    const f32x4 zero4 = {0.f, 0.f, 0.f, 0.f};
    float xv[2], mskv[2];
    float swr[2][4];
    f32x4 res[2][2];

#pragma unroll
    for (int nt = 0; nt < 2; nt++) {
        int gt = tbase + wave * 32 + nt * 16 + l16;
        int gx = min(max(gt, 0), T_DIM - 1);
        float v = x[(size_t)b * T_DIM + gx];
        mskv[nt] = (gt >= 0) ? 1.f : 0.f;
        xv[nt] = v * mskv[nt];
    }
#pragma unroll
    for (int mt = 0; mt < 2; mt++)
#pragma unroll
        for (int r = 0; r < 4; r++)
            swr[mt][r] = sw[mt * 16 + quad * 4 + r];
#pragma unroll
    for (int mt = 0; mt < 2; mt++)
#pragma unroll
        for (int nt = 0; nt < 2; nt++) {
#pragma unroll
            for (int r = 0; r < 4; r++) res[mt][nt][r] = swr[mt][r] * xv[nt];
            const int c = wave * 32 + nt * 16 + l16;
            const int ch0 = mt * 16 + quad * 4;
            unsigned h0 = pk2(res[mt][nt][0], res[mt][nt][1]);
            unsigned h1 = pk2(res[mt][nt][2], res[mt][nt][3]);
            *(uint2*)(act + c * AS + CH_RH + ch0) = make_uint2(h0, h1);
        }
    __syncthreads();

    const unsigned short* wl = wpk;
    for (int l = 0; l < NLAYERS; l++, wl += WPL2) {
        // conv B-frags (prv needs col-1 -> cross-wave; read BEFORE barrier)
        bf16x8 bc[2][2];   // [ks: prv/cur][nt]
#pragma unroll
        for (int nt = 0; nt < 2; nt++) {
            const int c = wave * 32 + nt * 16 + l16;
            const int cp = max(c - 1, 0);
            bc[0][nt] = *(const bf16x8*)(act + cp * AS + CH_RH + quad * 8);
            bc[1][nt] = *(const bf16x8*)(act + c  * AS + CH_RH + quad * 8);
        }
        __syncthreads();   // A: conv reads done before this layer's resb writes

        // GEMM1: y[32] = Wdil . [prv;cur]
        f32x4 acc1[2][2];
#pragma unroll
        for (int mt = 0; mt < 2; mt++)
#pragma unroll
            for (int nt = 0; nt < 2; nt++) acc1[mt][nt] = zero4;
#pragma unroll
        for (int ks = 0; ks < 2; ks++)
#pragma unroll
            for (int mt = 0; mt < 2; mt++) {
                bf16x8 a = *(const bf16x8*)(wl + (mt * 2 + ks) * 512 + lane * 8);
#pragma unroll
                for (int nt = 0; nt < 2; nt++)
                    acc1[mt][nt] = mfma16(a, bc[ks][nt], acc1[mt][nt]);
            }

        // y C-layout -> B-frag entirely in registers (pi order); swizzles
        // issued here, consumed after the independent h-part MFMAs below.
        bf16x8 by[2];
#pragma unroll
        for (int nt = 0; nt < 2; nt++) {
            union { unsigned u[4]; bf16x8 v; } cv;
            unsigned a0 = pk2(acc1[0][nt][0], acc1[0][nt][1]);
            unsigned b0 = pk2(acc1[0][nt][2], acc1[0][nt][3]);
            unsigned c0 = pk2(acc1[1][nt][0], acc1[1][nt][1]);
            unsigned d0 = pk2(acc1[1][nt][2], acc1[1][nt][3]);
            cv.u[0] = a0;
            cv.u[1] = (unsigned)__builtin_amdgcn_ds_swizzle((int)b0, 0x401F); // lane^16
            cv.u[2] = c0;
            cv.u[3] = (unsigned)__builtin_amdgcn_ds_swizzle((int)d0, 0x401F);
            by[nt] = cv.v;
        }

        // GEMM2: [f;g] = W . [y | h | 0]  (M=64, K=128)
        // h-part (kt=1..3, from LDS as in R0) first; y-part (regs) last.
        f32x4 acc2[4][2];
#pragma unroll
        for (int kt = 1; kt < 4; kt++) {
            bf16x8 bb[2];
#pragma unroll
            for (int nt = 0; nt < 2; nt++) {
                const int c = wave * 32 + nt * 16 + l16;
                bb[nt] = *(const bf16x8*)(act + c * AS + CH_Z + kt * 32 + quad * 8);
            }
#pragma unroll
            for (int mt = 0; mt < 4; mt++) {
                bf16x8 a = *(const bf16x8*)(wl + G2_OFF + (mt * 4 + kt) * 512 + lane * 8);
#pragma unroll
                for (int nt = 0; nt < 2; nt++)
                    acc2[mt][nt] = (kt == 1) ? mfma16(a, bb[nt], zero4)
                                             : mfma16(a, bb[nt], acc2[mt][nt]);
            }
        }
#pragma unroll
        for (int mt = 0; mt < 4; mt++) {
            bf16x8 a = *(const bf16x8*)(wl + G2_OFF + (mt * 4) * 512 + lane * 8);
#pragma unroll
            for (int nt = 0; nt < 2; nt++)
                acc2[mt][nt] = mfma16(a, by[nt], acc2[mt][nt]);
        }

        // glue: z = tanh(f)*sigmoid(g) with pre-scaled logits (exp2 form):
        // F=2log2e*f<=64, G=log2e*g<=22; z=(2^F-1)*2^G / ((2^F+1)(2^G+1));
        // denom <= 7.7e25 finite, single rcp, raw v_exp_f32 (1 trans op).
        bf16x8 bz[2];
#pragma unroll
        for (int nt = 0; nt < 2; nt++) {
            float z[2][4];
#pragma unroll
            for (int mt = 0; mt < 2; mt++)
#pragma unroll
                for (int r = 0; r < 4; r++) {
                    float fa = fminf(acc2[mt][nt][r], 64.f);
                    float ga = fminf(acc2[mt + 2][nt][r], 22.f);
                    float ef = __builtin_amdgcn_exp2f(fa);
                    float eg = __builtin_amdgcn_exp2f(ga);
                    float rr = __builtin_amdgcn_rcpf((ef + 1.f) * (eg + 1.f));
                    z[mt][r] = (ef - 1.f) * eg * rr;
                }
            union { unsigned u[4]; bf16x8 v; } cv;
            unsigned a0 = pk2(z[0][0], z[0][1]);
            unsigned b0 = pk2(z[0][2], z[0][3]);
            unsigned c0 = pk2(z[1][0], z[1][1]);
            unsigned d0 = pk2(z[1][2], z[1][3]);
            cv.u[0] = a0;
            cv.u[1] = (unsigned)__builtin_amdgcn_ds_swizzle((int)b0, 0x401F);
            cv.u[2] = c0;
            cv.u[3] = (unsigned)__builtin_amdgcn_ds_swizzle((int)d0, 0x401F);
            bz[nt] = cv.v;
        }

        // GEMM4: out[32] = Wout . z  (A packed in pi order)
        f32x4 acc4[2][2];
#pragma unroll
        for (int mt = 0; mt < 2; mt++) {
            bf16x8 a = *(const bf16x8*)(wl + G4_OFF + mt * 512 + lane * 8);
#pragma unroll
            for (int nt = 0; nt < 2; nt++)
                acc4[mt][nt] = mfma16(a, bz[nt], zero4);
        }

        // residual update (fp32 regs) + resb write; mask only on tile 0
#pragma unroll
        for (int mt = 0; mt < 2; mt++)
#pragma unroll
            for (int nt = 0; nt < 2; nt++) {
                const int c = wave * 32 + nt * 16 + l16;
                const int ch0 = mt * 16 + quad * 4;
                f32x4 nr = res[mt][nt] + acc4[mt][nt];
                if (tile0 && wave < 2) nr = nr * mskv[nt];   // block/wave-uniform branch
                res[mt][nt] = nr;
                unsigned h0 = pk2(nr[0], nr[1]);
                unsigned h1 = pk2(nr[2], nr[3]);
                *(uint2*)(act + c * AS + CH_RH + ch0) = make_uint2(h0, h1);
            }
        __syncthreads();   // B: resb writes visible before next layer's reads
    }

    // epilogue: skip = res_final - res_0 (cols >= HALO, in range)
#pragma unroll
    for (int mt = 0; mt < 2; mt++)
#pragma unroll
        for (int nt = 0; nt < 2; nt++) {
            const int c = wave * 32 + nt * 16 + l16;
            const int gt = tbase + c;
            if (c >= HALO && gt < T_DIM) {
#pragma unroll
                for (int r = 0; r < 4; r++) {
                    const int ch = mt * 16 + quad * 4 + r;
                    skip_out[((size_t)b * RC + ch) * T_DIM + gt] =
                        res[mt][nt][r] - swr[mt][r] * xv[nt];
                }
            }
        }
}

// ---- end: relu->e1->relu->e2 with MFMA (bf16). Block = 64 cols, M=256.
__global__ __launch_bounds__(256) void end_kernel(
    const float* __restrict__ skip,          // [B,32,T]
    const unsigned short* __restrict__ e1pk, // A-frags [16 mt][512]
    const unsigned short* __restrict__ e2pk, // A-frags [16 mt * 8 kf][512]
    float* __restrict__ outp)                // [B][256][T]
{
    __shared__ unsigned short sk_s[64 * 40];    // [col][ch], pad 32->40
    __shared__ unsigned short e_s[64 * 264];    // [col][s], pad 256->264

    const int tid  = threadIdx.x;
    const int lane = tid & 63;
    const int wave = tid >> 6;
    const int quad = lane >> 4;
    const int l16  = lane & 15;
    const int b  = blockIdx.x >> 8;
    const int t0 = (blockIdx.x & 255) * 64;

    // stage relu(skip) -> bf16 [col][ch]
    {
        const int col = tid & 63;
        const int cg = tid >> 6;           // 4 channel groups of 8
        const float* sp = skip + ((size_t)b * RC + cg * 8) * T_DIM + t0 + col;
        float v[8];
#pragma unroll
        for (int k = 0; k < 8; k++)
            v[k] = fmaxf(sp[(size_t)k * T_DIM], 0.f);
        unsigned u0 = pk2(v[0], v[1]), u1 = pk2(v[2], v[3]);
        unsigned u2 = pk2(v[4], v[5]), u3 = pk2(v[6], v[7]);
        *(uint2*)(sk_s + col * 40 + cg * 8)     = make_uint2(u0, u1);
        *(uint2*)(sk_s + col * 40 + cg * 8 + 4) = make_uint2(u2, u3);
    }
    __syncthreads();

    // phase 1: e[256 s][64 col] = relu(e1 . sk) ; wave handles 4 m-tiles
    {
        bf16x8 bb[4];
#pragma unroll
        for (int ntl = 0; ntl < 4; ntl++)
            bb[ntl] = *(const bf16x8*)(sk_s + (ntl * 16 + l16) * 40 + quad * 8);
#pragma unroll
        for (int mtl = 0; mtl < 4; mtl++) {
            const int mt = wave * 4 + mtl;
            bf16x8 a = *(const bf16x8*)(e1pk + mt * 512 + lane * 8);
            f32x4 acc[4];
#pragma unroll
            for (int ntl = 0; ntl < 4; ntl++) {
                acc[ntl] = mfma16(a, bb[ntl], (f32x4){0.f, 0.f, 0.f, 0.f});
            }
#pragma unroll
            for (int ntl = 0; ntl < 4; ntl++) {
                const int col = ntl * 16 + l16;
                unsigned p0 = pk2(fmaxf(acc[ntl][0], 0.f), fmaxf(acc[ntl][1], 0.f));
                unsigned p1 = pk2(fmaxf(acc[ntl][2], 0.f), fmaxf(acc[ntl][3], 0.f));
                *(uint2*)(e_s + col * 264 + mt * 16 + quad * 4) = make_uint2(p0, p1);
            }
        }
    }
    __syncthreads();

    // phase 2: logits[256 cls][64 col] = e2 . e ; wave: 4 m-tiles x 4 n x 8 k
    {
        f32x4 acc[4][4];
#pragma unroll
        for (int mtl = 0; mtl < 4; mtl++)
#pragma unroll
            for (int ntl = 0; ntl < 4; ntl++) acc[mtl][ntl] = (f32x4){0.f, 0.f, 0.f, 0.f};

        for (int kf = 0; kf < 8; kf++) {
            bf16x8 bb[4];
#pragma unroll
            for (int ntl = 0; ntl < 4; ntl++)
                bb[ntl] = *(const bf16x8*)(e_s + (ntl * 16 + l16) * 264 + kf * 32 + quad * 8);
#pragma unroll
            for (int mtl = 0; mtl < 4; mtl++) {
                const int mt = wave * 4 + mtl;
                bf16x8 a = *(const bf16x8*)(e2pk + (mt * 8 + kf) * 512 + lane * 8);
#pragma unroll
                for (int ntl = 0; ntl < 4; ntl++)
                    acc[mtl][ntl] = mfma16(a, bb[ntl], acc[mtl][ntl]);
            }
        }

#pragma unroll
        for (int mtl = 0; mtl < 4; mtl++)
#pragma unroll
            for (int ntl = 0; ntl < 4; ntl++) {
                const int cls0 = (wave * 4 + mtl) * 16 + quad * 4;
                const int col = ntl * 16 + l16;
#pragma unroll
                for (int r = 0; r < 4; r++)
                    outp[((size_t)b * CLASSES + cls0 + r) * T_DIM + t0 + col] =
                        acc[mtl][ntl][r];
            }
    }
}

extern "C" void kernel_launch(void* const* d_in, const int* in_sizes, int n_in,
                              void* d_out, int out_size, void* d_ws, size_t ws_size,
                              hipStream_t stream) {
    const float* x   = (const float*)d_in[0];
    const float* h   = (const float*)d_in[1];
    const float* sw  = (const float*)d_in[2];
    const float* dw  = (const float*)d_in[3];
    const float* fw  = (const float*)d_in[4];
    const float* gw  = (const float*)d_in[5];
    const float* cfw = (const float*)d_in[6];
    const float* cgw = (const float*)d_in[7];
    const float* ow  = (const float*)d_in[8];
    const float* e1  = (const float*)d_in[9];
    const float* e2  = (const float*)d_in[10];
    float* out = (float*)d_out;

    const size_t SKIP_N = (size_t)B_DIM * RC * T_DIM;   // 2,097,152 floats
    float* skip = (float*)d_ws;
    unsigned short* wpk  = (unsigned short*)(skip + SKIP_N);
    unsigned short* e1pk = wpk + (size_t)NLAYERS * WPL2;
    unsigned short* e2pk = e1pk + 16 * 512;

    // 450,560 + 8,192 + 65,536 = 524,288 -> 2048 blocks exactly
    pack_kernel<<<2048, 256, 0, stream>>>(dw, fw, gw, cfw, cgw, ow, e1, e2,
                                          wpk, e1pk, e2pk);

    fused_mfma_kernel<<<B_DIM * NT, 256, 0, stream>>>(x, h, sw, wpk, skip);

    end_kernel<<<B_DIM * 256, 256, 0, stream>>>(skip, e1pk, e2pk, out);
}